// Round 1
// baseline (460.242 us; speedup 1.0000x reference)
//
#include <hip/hip_runtime.h>
#include <hip/hip_bf16.h>
#include <math.h>

// MoE top-2: B=4,S=2048,H=1024,E=8,K=2. fp32 in/out, f16 MFMA compute.
#define TOK 8192
#define HD 1024
#define NE 8

typedef _Float16 half8 __attribute__((ext_vector_type(8)));
typedef _Float16 half4v __attribute__((ext_vector_type(4)));
typedef float floatx4 __attribute__((ext_vector_type(4)));

// ---------------- Router: one wave per token ----------------
__global__ void moe_router(const float* __restrict__ x,
                           const float* __restrict__ rw,
                           const float* __restrict__ rb,
                           int* __restrict__ cnt,
                           int* __restrict__ tok_list,
                           float* __restrict__ tok_w) {
  const int lane = threadIdx.x & 63;
  const int wid = threadIdx.x >> 6;
  const int t = blockIdx.x * 4 + wid;
  const float* xp = x + (size_t)t * HD;
  float xr[16];
#pragma unroll
  for (int i = 0; i < 16; ++i) xr[i] = xp[lane + 64 * i];
  float sc[NE];
#pragma unroll
  for (int e = 0; e < NE; ++e) {
    const float* wp = rw + e * HD;
    float a = 0.f;
#pragma unroll
    for (int i = 0; i < 16; ++i) a += xr[i] * wp[lane + 64 * i];
#pragma unroll
    for (int off = 32; off > 0; off >>= 1) a += __shfl_xor(a, off);
    sc[e] = a + rb[e];
  }
  // top-2, strict > so ties pick lowest index (matches jax.lax.top_k)
  float b1 = sc[0]; int e1 = 0;
#pragma unroll
  for (int e = 1; e < NE; ++e) if (sc[e] > b1) { b1 = sc[e]; e1 = e; }
  float b2 = -1e30f; int e2 = 0;
#pragma unroll
  for (int e = 0; e < NE; ++e) { if (e != e1 && sc[e] > b2) { b2 = sc[e]; e2 = e; } }
  if (lane == 0) {
    // renormalized top-2 softmax weights: p1/(p1+p2) = 1/(1+exp(s2-s1))
    float w1 = 1.f / (1.f + expf(b2 - b1));
    float w2 = 1.f - w1;
    int s1 = atomicAdd(&cnt[e1], 1);
    tok_list[e1 * TOK + s1] = t;
    tok_w[e1 * TOK + s1] = w1;
    int s2 = atomicAdd(&cnt[e2], 1);
    tok_list[e2 * TOK + s2] = t;
    tok_w[e2 * TOK + s2] = w2;
  }
}

// ---------------- fp32 -> f16 pre-convert ----------------
__global__ void cvt_f32_f16(const float* __restrict__ src,
                            _Float16* __restrict__ dst, int n4) {
  int i = blockIdx.x * 256 + threadIdx.x;
  if (i >= n4) return;
  float4 v = ((const float4*)src)[i];
  half4v h = {(_Float16)v.x, (_Float16)v.y, (_Float16)v.z, (_Float16)v.w};
  ((half4v*)dst)[i] = h;
}

// ---------------- Grouped expert GEMM ----------------
// MODE 1: f16 preconverted sources (Ah/Bh). MODE 0: fp32 sources (Af/Bf),
// converted inline while staging to LDS. 128x128 tile, BK=32, 4 waves,
// each wave 4x4 frags of mfma_f32_16x16x32_f16.
template <int MODE>
__global__ __launch_bounds__(256) void moe_gemm(
    const _Float16* __restrict__ Ah, const _Float16* __restrict__ Bh,
    const float* __restrict__ Af, const float* __restrict__ Bf,
    const float* __restrict__ eb,
    const int* __restrict__ cnt,
    const int* __restrict__ tok_list, const float* __restrict__ tok_w,
    float* __restrict__ out) {
  const int e = blockIdx.z;
  const int ce = cnt[e];
  const int m0 = blockIdx.y * 128;
  if (m0 >= ce) return;
  const int n0 = blockIdx.x * 128;
  const int tid = threadIdx.x;
  const int lane = tid & 63;
  const int wid = tid >> 6;
  const int wm = wid & 1, wn = wid >> 1;

  __shared__ _Float16 A_s[128 * 32];
  __shared__ _Float16 B_s[128 * 32];
  __shared__ int tok_s[128];
  __shared__ float w_s[128];

  if (tid < 128) {
    int gr = m0 + tid;
    int tk = 0; float w = 0.f;
    if (gr < ce) { tk = tok_list[e * TOK + gr]; w = tok_w[e * TOK + gr]; }
    tok_s[tid] = tk; w_s[tid] = w;
  }
  __syncthreads();

  floatx4 acc[4][4];
  floatx4 zero = {0.f, 0.f, 0.f, 0.f};
#pragma unroll
  for (int i = 0; i < 4; ++i)
#pragma unroll
    for (int j = 0; j < 4; ++j) acc[i][j] = zero;

  const size_t wbase = (size_t)e * HD * HD;

  for (int k0 = 0; k0 < HD; k0 += 32) {
    if (MODE == 1) {
#pragma unroll
      for (int q = 0; q < 2; ++q) {
        int s = tid + 256 * q;       // 0..511
        int row = s >> 2, kc = (s & 3) * 8;
        int tk = tok_s[row];
        *(half8*)&A_s[row * 32 + kc] =
            *(const half8*)(Ah + (size_t)tk * HD + k0 + kc);
        *(half8*)&B_s[row * 32 + kc] =
            *(const half8*)(Bh + wbase + (size_t)(n0 + row) * HD + k0 + kc);
      }
    } else {
#pragma unroll
      for (int q = 0; q < 4; ++q) {
        int s = tid + 256 * q;       // 0..1023
        int row = s >> 3, kc = (s & 7) * 4;
        int tk = tok_s[row];
        float4 va = *(const float4*)(Af + (size_t)tk * HD + k0 + kc);
        half4v ha = {(_Float16)va.x, (_Float16)va.y, (_Float16)va.z, (_Float16)va.w};
        *(half4v*)&A_s[row * 32 + kc] = ha;
        float4 vb = *(const float4*)(Bf + wbase + (size_t)(n0 + row) * HD + k0 + kc);
        half4v hb = {(_Float16)vb.x, (_Float16)vb.y, (_Float16)vb.z, (_Float16)vb.w};
        *(half4v*)&B_s[row * 32 + kc] = hb;
      }
    }
    __syncthreads();
    half8 afr[4], bfr[4];
#pragma unroll
    for (int i = 0; i < 4; ++i)
      afr[i] = *(const half8*)&A_s[(wm * 64 + i * 16 + (lane & 15)) * 32 + (lane >> 4) * 8];
#pragma unroll
    for (int j = 0; j < 4; ++j)
      bfr[j] = *(const half8*)&B_s[(wn * 64 + j * 16 + (lane & 15)) * 32 + (lane >> 4) * 8];
#pragma unroll
    for (int i = 0; i < 4; ++i)
#pragma unroll
      for (int j = 0; j < 4; ++j)
        acc[i][j] = __builtin_amdgcn_mfma_f32_16x16x32_f16(afr[i], bfr[j], acc[i][j], 0, 0, 0);
    __syncthreads();
  }

  // epilogue: C/D layout col=lane&15, row=(lane>>4)*4+reg
#pragma unroll
  for (int j = 0; j < 4; ++j) {
    int col = n0 + wn * 64 + j * 16 + (lane & 15);
    float bias = eb[e * HD + col];
#pragma unroll
    for (int i = 0; i < 4; ++i) {
      int rbase = wm * 64 + i * 16 + ((lane >> 4) << 2);
#pragma unroll
      for (int r = 0; r < 4; ++r) {
        int row = rbase + r;
        if (m0 + row < ce) {
          int tk = tok_s[row];
          float wt = w_s[row];
          atomicAdd(&out[(size_t)tk * HD + col], wt * (acc[i][j][r] + bias));
        }
      }
    }
  }
}

extern "C" void kernel_launch(void* const* d_in, const int* in_sizes, int n_in,
                              void* d_out, int out_size, void* d_ws, size_t ws_size,
                              hipStream_t stream) {
  (void)in_sizes; (void)n_in;
  const float* x  = (const float*)d_in[0];
  const float* rw = (const float*)d_in[1];
  const float* rb = (const float*)d_in[2];
  const float* ew = (const float*)d_in[3];
  const float* eb = (const float*)d_in[4];
  float* out = (float*)d_out;

  // ws layout
  int*   cnt      = (int*)d_ws;                                  // 8 ints (256B reserved)
  int*   tok_list = (int*)((char*)d_ws + 256);                   // 8*8192*4
  float* tok_w    = (float*)((char*)d_ws + 256 + NE * TOK * 4);  // 8*8192*4
  size_t half_off = (256 + 2ull * NE * TOK * 4 + 255) & ~255ull;
  size_t need_fast = half_off + ((size_t)TOK * HD + (size_t)NE * HD * HD) * sizeof(_Float16);
  bool fast = ws_size >= need_fast;

  hipMemsetAsync(cnt, 0, NE * sizeof(int), stream);
  hipMemsetAsync(d_out, 0, (size_t)out_size * sizeof(float), stream);

  moe_router<<<TOK / 4, 256, 0, stream>>>(x, rw, rb, cnt, tok_list, tok_w);

  dim3 grid(HD / 128, TOK / 128, NE);  // (ntiles=8, mtiles max=64, experts=8)
  if (fast) {
    _Float16* xh = (_Float16*)((char*)d_ws + half_off);
    _Float16* wh = xh + (size_t)TOK * HD;
    int n4x = TOK * HD / 4;
    int n4w = NE * HD * HD / 4;
    cvt_f32_f16<<<(n4x + 255) / 256, 256, 0, stream>>>(x, xh, n4x);
    cvt_f32_f16<<<(n4w + 255) / 256, 256, 0, stream>>>(ew, wh, n4w);
    moe_gemm<1><<<grid, 256, 0, stream>>>(xh, wh, nullptr, nullptr, eb, cnt,
                                          tok_list, tok_w, out);
  } else {
    moe_gemm<0><<<grid, 256, 0, stream>>>(nullptr, nullptr, x, ew, eb, cnt,
                                          tok_list, tok_w, out);
  }
}

// Round 2
// 279.744 us; speedup vs baseline: 1.6452x; 1.6452x over previous
//
#include <hip/hip_runtime.h>
#include <hip/hip_bf16.h>
#include <math.h>

// MoE top-2: B=4,S=2048,H=1024,E=8,K=2. fp32 in/out, f16 MFMA compute.
#define TOK 8192
#define HD 1024
#define NE 8

typedef _Float16 half8 __attribute__((ext_vector_type(8)));
typedef _Float16 half4v __attribute__((ext_vector_type(4)));
typedef float floatx4 __attribute__((ext_vector_type(4)));

// ---------------- Score: one wave per token, no atomics ----------------
__global__ void moe_score(const float* __restrict__ x,
                          const float* __restrict__ rw,
                          const float* __restrict__ rb,
                          int* __restrict__ epair,
                          float* __restrict__ w1out) {
  const int lane = threadIdx.x & 63;
  const int wid = threadIdx.x >> 6;
  const int t = blockIdx.x * 4 + wid;
  const float4* xp = (const float4*)(x + (size_t)t * HD);
  float4 xr[4];
#pragma unroll
  for (int i = 0; i < 4; ++i) xr[i] = xp[lane + 64 * i];
  float sc[NE];
#pragma unroll
  for (int e = 0; e < NE; ++e) {
    const float4* wp = (const float4*)(rw + e * HD);
    float a = 0.f;
#pragma unroll
    for (int i = 0; i < 4; ++i) {
      float4 w = wp[lane + 64 * i];
      a += xr[i].x * w.x + xr[i].y * w.y + xr[i].z * w.z + xr[i].w * w.w;
    }
#pragma unroll
    for (int off = 32; off > 0; off >>= 1) a += __shfl_xor(a, off);
    sc[e] = a + rb[e];
  }
  // top-2, strict > so ties pick lowest index (matches jax.lax.top_k)
  float b1 = sc[0]; int e1 = 0;
#pragma unroll
  for (int e = 1; e < NE; ++e) if (sc[e] > b1) { b1 = sc[e]; e1 = e; }
  float b2 = -1e30f; int e2 = 0;
#pragma unroll
  for (int e = 0; e < NE; ++e) { if (e != e1 && sc[e] > b2) { b2 = sc[e]; e2 = e; } }
  if (lane == 0) {
    // renormalized top-2 softmax weights: p1/(p1+p2) = 1/(1+exp(s2-s1))
    epair[t] = e1 | (e2 << 8);
    w1out[t] = 1.f / (1.f + expf(b2 - b1));
  }
}

// ---------------- Scatter: block-aggregated, 256 global atomics total ------
__global__ void moe_scatter(const int* __restrict__ epair,
                            const float* __restrict__ w1in,
                            int* __restrict__ cntp,        // padded: cntp[e*64]
                            int* __restrict__ tok_list,
                            float* __restrict__ tok_w) {
  __shared__ int lcnt[NE];
  __shared__ int lbase[NE];
  const int tid = threadIdx.x;
  const int t = blockIdx.x * 256 + tid;
  if (tid < NE) lcnt[tid] = 0;
  __syncthreads();
  int ep = epair[t];
  int e1 = ep & 0xff, e2 = ep >> 8;
  float w1 = w1in[t];
  int o1 = atomicAdd(&lcnt[e1], 1);
  int o2 = atomicAdd(&lcnt[e2], 1);
  __syncthreads();
  if (tid < NE) lbase[tid] = atomicAdd(&cntp[tid * 64], lcnt[tid]);
  __syncthreads();
  int p1 = lbase[e1] + o1;
  tok_list[e1 * TOK + p1] = t;
  tok_w[e1 * TOK + p1] = w1;
  int p2 = lbase[e2] + o2;
  tok_list[e2 * TOK + p2] = t;
  tok_w[e2 * TOK + p2] = 1.f - w1;
}

// ---------------- fp32 -> f16 pre-convert ----------------
__global__ void cvt_f32_f16(const float* __restrict__ src,
                            _Float16* __restrict__ dst, int n4) {
  int i = blockIdx.x * 256 + threadIdx.x;
  if (i >= n4) return;
  float4 v = ((const float4*)src)[i];
  half4v h = {(_Float16)v.x, (_Float16)v.y, (_Float16)v.z, (_Float16)v.w};
  ((half4v*)dst)[i] = h;
}

// ---------------- Grouped expert GEMM ----------------
// MODE 1: f16 preconverted sources, async global_load_lds staging (16B/lane).
// MODE 0: fp32 sources converted inline while staging (fallback).
// 128x128 tile, BK=32, 4 waves, each wave 4x4 frags of mfma_f32_16x16x32_f16.
template <int MODE>
__global__ __launch_bounds__(256) void moe_gemm(
    const _Float16* __restrict__ Ah, const _Float16* __restrict__ Bh,
    const float* __restrict__ Af, const float* __restrict__ Bf,
    const float* __restrict__ eb,
    const int* __restrict__ cntp,
    const int* __restrict__ tok_list, const float* __restrict__ tok_w,
    float* __restrict__ out) {
  const int e = blockIdx.z;
  const int ce = cntp[e * 64];
  const int m0 = blockIdx.y * 128;
  if (m0 >= ce) return;
  const int n0 = blockIdx.x * 128;
  const int tid = threadIdx.x;
  const int lane = tid & 63;
  const int wid = tid >> 6;
  const int wm = wid & 1, wn = wid >> 1;

  __shared__ _Float16 A_s[128 * 32];
  __shared__ _Float16 B_s[128 * 32];
  __shared__ int tok_s[128];
  __shared__ float w_s[128];

  if (tid < 128) {
    int gr = m0 + tid;
    int tk = 0; float w = 0.f;
    if (gr < ce) { tk = tok_list[e * TOK + gr]; w = tok_w[e * TOK + gr]; }
    tok_s[tid] = tk; w_s[tid] = w;
  }
  __syncthreads();

  floatx4 acc[4][4];
  floatx4 zero = {0.f, 0.f, 0.f, 0.f};
#pragma unroll
  for (int i = 0; i < 4; ++i)
#pragma unroll
    for (int j = 0; j < 4; ++j) acc[i][j] = zero;

  const size_t wbase = (size_t)e * HD * HD;

  for (int k0 = 0; k0 < HD; k0 += 32) {
    if (MODE == 1) {
      // Async staging: each wave q-round moves 1024B = 16 rows (64B/row).
      // LDS dest = wave-uniform base + lane*16 (HW rule); our row-major
      // 32-half rows are exactly contiguous in that order.
      const int sub = lane & 3;          // 16B chunk within row
      const int rloc = lane >> 2;        // row within 16-row group
#pragma unroll
      for (int q = 0; q < 2; ++q) {
        const int r0 = (q * 4 + wid) * 16;
        const int row = r0 + rloc;
        const _Float16* ga = Ah + (size_t)tok_s[row] * HD + k0 + sub * 8;
        __builtin_amdgcn_global_load_lds(
            (const __attribute__((address_space(1))) unsigned int*)ga,
            (__attribute__((address_space(3))) unsigned int*)&A_s[r0 * 32],
            16, 0, 0);
        const _Float16* gb = Bh + wbase + (size_t)(n0 + row) * HD + k0 + sub * 8;
        __builtin_amdgcn_global_load_lds(
            (const __attribute__((address_space(1))) unsigned int*)gb,
            (__attribute__((address_space(3))) unsigned int*)&B_s[r0 * 32],
            16, 0, 0);
      }
    } else {
#pragma unroll
      for (int q = 0; q < 4; ++q) {
        int s = tid + 256 * q;       // 0..1023
        int row = s >> 3, kc = (s & 7) * 4;
        int tk = tok_s[row];
        float4 va = *(const float4*)(Af + (size_t)tk * HD + k0 + kc);
        half4v ha = {(_Float16)va.x, (_Float16)va.y, (_Float16)va.z, (_Float16)va.w};
        *(half4v*)&A_s[row * 32 + kc] = ha;
        float4 vb = *(const float4*)(Bf + wbase + (size_t)(n0 + row) * HD + k0 + kc);
        half4v hb = {(_Float16)vb.x, (_Float16)vb.y, (_Float16)vb.z, (_Float16)vb.w};
        *(half4v*)&B_s[row * 32 + kc] = hb;
      }
    }
    __syncthreads();
    half8 afr[4], bfr[4];
#pragma unroll
    for (int i = 0; i < 4; ++i)
      afr[i] = *(const half8*)&A_s[(wm * 64 + i * 16 + (lane & 15)) * 32 + (lane >> 4) * 8];
#pragma unroll
    for (int j = 0; j < 4; ++j)
      bfr[j] = *(const half8*)&B_s[(wn * 64 + j * 16 + (lane & 15)) * 32 + (lane >> 4) * 8];
#pragma unroll
    for (int i = 0; i < 4; ++i)
#pragma unroll
      for (int j = 0; j < 4; ++j)
        acc[i][j] = __builtin_amdgcn_mfma_f32_16x16x32_f16(afr[i], bfr[j], acc[i][j], 0, 0, 0);
    __syncthreads();
  }

  // epilogue: C/D layout col=lane&15, row=(lane>>4)*4+reg
#pragma unroll
  for (int j = 0; j < 4; ++j) {
    int col = n0 + wn * 64 + j * 16 + (lane & 15);
    float bias = eb[e * HD + col];
#pragma unroll
    for (int i = 0; i < 4; ++i) {
      int rbase = wm * 64 + i * 16 + ((lane >> 4) << 2);
#pragma unroll
      for (int r = 0; r < 4; ++r) {
        int row = rbase + r;
        if (m0 + row < ce) {
          int tk = tok_s[row];
          float wt = w_s[row];
          atomicAdd(&out[(size_t)tk * HD + col], wt * (acc[i][j][r] + bias));
        }
      }
    }
  }
}

extern "C" void kernel_launch(void* const* d_in, const int* in_sizes, int n_in,
                              void* d_out, int out_size, void* d_ws, size_t ws_size,
                              hipStream_t stream) {
  (void)in_sizes; (void)n_in;
  const float* x  = (const float*)d_in[0];
  const float* rw = (const float*)d_in[1];
  const float* rb = (const float*)d_in[2];
  const float* ew = (const float*)d_in[3];
  const float* eb = (const float*)d_in[4];
  float* out = (float*)d_out;

  // ws layout
  int*   cntp     = (int*)d_ws;                            // NE*64 ints padded (2 KB)
  size_t off = 2048;
  int*   tok_list = (int*)((char*)d_ws + off);  off += (size_t)NE * TOK * 4;
  float* tok_w    = (float*)((char*)d_ws + off); off += (size_t)NE * TOK * 4;
  int*   epair    = (int*)((char*)d_ws + off);  off += (size_t)TOK * 4;
  float* w1buf    = (float*)((char*)d_ws + off); off += (size_t)TOK * 4;
  size_t half_off = (off + 255) & ~255ull;
  size_t need_fast = half_off + ((size_t)TOK * HD + (size_t)NE * HD * HD) * sizeof(_Float16);
  bool fast = ws_size >= need_fast;

  hipMemsetAsync(cntp, 0, NE * 64 * sizeof(int), stream);
  hipMemsetAsync(d_out, 0, (size_t)out_size * sizeof(float), stream);

  moe_score<<<TOK / 4, 256, 0, stream>>>(x, rw, rb, epair, w1buf);
  moe_scatter<<<TOK / 256, 256, 0, stream>>>(epair, w1buf, cntp, tok_list, tok_w);

  dim3 grid(HD / 128, TOK / 128, NE);  // (ntiles=8, mtiles max=64, experts=8)
  if (fast) {
    _Float16* xh = (_Float16*)((char*)d_ws + half_off);
    _Float16* wh = xh + (size_t)TOK * HD;
    int n4x = TOK * HD / 4;
    int n4w = NE * HD * HD / 4;
    cvt_f32_f16<<<(n4x + 255) / 256, 256, 0, stream>>>(x, xh, n4x);
    cvt_f32_f16<<<(n4w + 255) / 256, 256, 0, stream>>>(ew, wh, n4w);
    moe_gemm<1><<<grid, 256, 0, stream>>>(xh, wh, nullptr, nullptr, eb, cntp,
                                          tok_list, tok_w, out);
  } else {
    moe_gemm<0><<<grid, 256, 0, stream>>>(nullptr, nullptr, x, ew, eb, cntp,
                                          tok_list, tok_w, out);
  }
}

// Round 3
// 207.305 us; speedup vs baseline: 2.2201x; 1.3494x over previous
//
#include <hip/hip_runtime.h>
#include <hip/hip_bf16.h>
#include <math.h>

// MoE top-2: B=4,S=2048,H=1024,E=8,K=2. fp32 in/out, f16 MFMA compute.
#define TOK 8192
#define HD 1024
#define NE 8
#define SLOTS 17408   // 16384 + per-expert 128-pad

typedef _Float16 half8 __attribute__((ext_vector_type(8)));
typedef _Float16 half4v __attribute__((ext_vector_type(4)));
typedef float floatx4 __attribute__((ext_vector_type(4)));

// ---- Score: one wave per token; also emits x in f16 (fused cvt) ----
__global__ void moe_score(const float* __restrict__ x,
                          const float* __restrict__ rw,
                          const float* __restrict__ rb,
                          int* __restrict__ epair,
                          float* __restrict__ w1out,
                          _Float16* __restrict__ xh) {
  const int lane = threadIdx.x & 63;
  const int wid = threadIdx.x >> 6;
  const int t = blockIdx.x * 4 + wid;
  const float4* xp = (const float4*)(x + (size_t)t * HD);
  float4 xr[4];
#pragma unroll
  for (int i = 0; i < 4; ++i) xr[i] = xp[lane + 64 * i];
  if (xh) {
    _Float16* xo = xh + (size_t)t * HD;
#pragma unroll
    for (int i = 0; i < 4; ++i) {
      half4v h = {(_Float16)xr[i].x, (_Float16)xr[i].y,
                  (_Float16)xr[i].z, (_Float16)xr[i].w};
      *(half4v*)(xo + (lane + 64 * i) * 4) = h;
    }
  }
  float sc[NE];
#pragma unroll
  for (int e = 0; e < NE; ++e) {
    const float4* wp = (const float4*)(rw + e * HD);
    float a = 0.f;
#pragma unroll
    for (int i = 0; i < 4; ++i) {
      float4 w = wp[lane + 64 * i];
      a += xr[i].x * w.x + xr[i].y * w.y + xr[i].z * w.z + xr[i].w * w.w;
    }
#pragma unroll
    for (int off = 32; off > 0; off >>= 1) a += __shfl_xor(a, off);
    sc[e] = a + rb[e];
  }
  float b1 = sc[0]; int e1 = 0;
#pragma unroll
  for (int e = 1; e < NE; ++e) if (sc[e] > b1) { b1 = sc[e]; e1 = e; }
  float b2 = -1e30f; int e2 = 0;
#pragma unroll
  for (int e = 0; e < NE; ++e) { if (e != e1 && sc[e] > b2) { b2 = sc[e]; e2 = e; } }
  if (lane == 0) {
    epair[t] = e1 | (e2 << 8);
    w1out[t] = 1.f / (1.f + expf(b2 - b1));  // renormalized top-2 softmax
  }
}

// ---- Count: per-expert totals, 32 blocks x 8 global atomics ----
__global__ void moe_count(const int* __restrict__ epair, int* __restrict__ cntp) {
  __shared__ int lc[NE];
  const int tid = threadIdx.x;
  if (tid < NE) lc[tid] = 0;
  __syncthreads();
  int ep = epair[blockIdx.x * 256 + tid];
  atomicAdd(&lc[ep & 0xff], 1);
  atomicAdd(&lc[ep >> 8], 1);
  __syncthreads();
  if (tid < NE) atomicAdd(&cntp[tid * 64], lc[tid]);
}

// ---- Prefix: 128-aligned compacted slot bases ----
__global__ void moe_prefix(const int* __restrict__ cntp, int* __restrict__ cnt2,
                           int* __restrict__ base) {
  if (threadIdx.x == 0) {
    int b = 0;
    for (int e = 0; e < NE; ++e) {
      base[e] = b;
      cnt2[e * 64] = b;
      b += (cntp[e * 64] + 127) & ~127;
    }
  }
}

// ---- Scatter: slot-compacted token lists + per-token slot map ----
__global__ void moe_scatter(const int* __restrict__ epair,
                            const float* __restrict__ w1in,
                            int* __restrict__ cnt2,
                            int* __restrict__ tok_list,
                            float* __restrict__ tok_w,
                            int* __restrict__ slot_of) {
  __shared__ int lcnt[NE];
  __shared__ int lbase[NE];
  const int tid = threadIdx.x;
  const int t = blockIdx.x * 256 + tid;
  if (tid < NE) lcnt[tid] = 0;
  __syncthreads();
  int ep = epair[t];
  int e1 = ep & 0xff, e2 = ep >> 8;
  float w1 = w1in[t];
  int o1 = atomicAdd(&lcnt[e1], 1);
  int o2 = atomicAdd(&lcnt[e2], 1);
  __syncthreads();
  if (tid < NE) lbase[tid] = atomicAdd(&cnt2[tid * 64], lcnt[tid]);
  __syncthreads();
  int s1 = lbase[e1] + o1;
  tok_list[s1] = t; tok_w[s1] = w1; slot_of[2 * t] = s1;
  int s2 = lbase[e2] + o2;
  tok_list[s2] = t; tok_w[s2] = 1.f - w1; slot_of[2 * t + 1] = s2;
}

// ---- fp32 -> f16 pre-convert (expert weights) ----
__global__ void cvt_f32_f16(const float* __restrict__ src,
                            _Float16* __restrict__ dst, int n4) {
  int i = blockIdx.x * 256 + threadIdx.x;
  if (i >= n4) return;
  float4 v = ((const float4*)src)[i];
  half4v h = {(_Float16)v.x, (_Float16)v.y, (_Float16)v.z, (_Float16)v.w};
  ((half4v*)dst)[i] = h;
}

// ---- Grouped expert GEMM: 128x128 tile, BK=64, swizzled LDS ----
// EPI=1: f16 store to compacted scratch; EPI=0: fp32 atomicAdd to out.
template <int EPI>
__global__ __launch_bounds__(256) void moe_gemm(
    const _Float16* __restrict__ Ah, const _Float16* __restrict__ Bh,
    const float* __restrict__ eb,
    const int* __restrict__ cntp, const int* __restrict__ base,
    const int* __restrict__ tok_list, const float* __restrict__ tok_w,
    _Float16* __restrict__ scratch, float* __restrict__ out) {
  const int e = blockIdx.z;
  const int ce = cntp[e * 64];
  const int m0 = blockIdx.y * 128;
  if (m0 >= ce) return;
  const int sbase = base[e];
  const int n0 = blockIdx.x * 128;
  const int tid = threadIdx.x;
  const int lane = tid & 63;
  const int wid = tid >> 6;
  const int wm = wid & 1, wn = wid >> 1;

  __shared__ _Float16 A_s[128 * 64];
  __shared__ _Float16 B_s[128 * 64];
  __shared__ int tok_s[128];
  __shared__ float w_s[128];

  if (tid < 128) {
    int tk = 0; float w = 0.f;
    if (m0 + tid < ce) { tk = tok_list[sbase + m0 + tid]; w = tok_w[sbase + m0 + tid]; }
    tok_s[tid] = tk; w_s[tid] = w;
  }
  __syncthreads();

  floatx4 acc[4][4];
  floatx4 zero = {0.f, 0.f, 0.f, 0.f};
#pragma unroll
  for (int i = 0; i < 4; ++i)
#pragma unroll
    for (int j = 0; j < 4; ++j) acc[i][j] = zero;

  const size_t wbase = (size_t)e * HD * HD;
  // staging geometry: 4 rounds x 8 rows/wave; lane = rloc*8+sub (16B chunks)
  const int rloc = lane >> 3, sub = lane & 7;
  const int csw = (sub ^ rloc) * 8;  // XOR-swizzled chunk (element offset)
  size_t agbase[4], bgbase[4];
#pragma unroll
  for (int q = 0; q < 4; ++q) {
    int row = wid * 32 + q * 8 + rloc;
    agbase[q] = (size_t)tok_s[row] * HD + csw;
    bgbase[q] = wbase + (size_t)(n0 + row) * HD + csw;
  }
  const int x7 = lane & 7, q4 = lane >> 4;

  for (int k0 = 0; k0 < HD; k0 += 64) {
#pragma unroll
    for (int q = 0; q < 4; ++q) {
      const int r0 = wid * 32 + q * 8;
      __builtin_amdgcn_global_load_lds(
          (const __attribute__((address_space(1))) unsigned int*)(Ah + agbase[q] + k0),
          (__attribute__((address_space(3))) unsigned int*)&A_s[r0 * 64], 16, 0, 0);
      __builtin_amdgcn_global_load_lds(
          (const __attribute__((address_space(1))) unsigned int*)(Bh + bgbase[q] + k0),
          (__attribute__((address_space(3))) unsigned int*)&B_s[r0 * 64], 16, 0, 0);
    }
    __syncthreads();
#pragma unroll
    for (int kf = 0; kf < 2; ++kf) {
      half8 afr[4], bfr[4];
      const int cc = kf * 4 + q4;
#pragma unroll
      for (int i = 0; i < 4; ++i)
        afr[i] = *(const half8*)&A_s[(wm * 64 + i * 16 + (lane & 15)) * 64 + ((cc ^ x7) * 8)];
#pragma unroll
      for (int j = 0; j < 4; ++j)
        bfr[j] = *(const half8*)&B_s[(wn * 64 + j * 16 + (lane & 15)) * 64 + ((cc ^ x7) * 8)];
#pragma unroll
      for (int i = 0; i < 4; ++i)
#pragma unroll
        for (int j = 0; j < 4; ++j)
          acc[i][j] = __builtin_amdgcn_mfma_f32_16x16x32_f16(afr[i], bfr[j], acc[i][j], 0, 0, 0);
    }
    __syncthreads();
  }

  // epilogue: C/D layout col=lane&15, row=(lane>>4)*4+reg
#pragma unroll
  for (int j = 0; j < 4; ++j) {
    int col = n0 + wn * 64 + j * 16 + (lane & 15);
    float bias = eb[e * HD + col];
#pragma unroll
    for (int i = 0; i < 4; ++i) {
      int rbase = wm * 64 + i * 16 + (q4 << 2);
#pragma unroll
      for (int r = 0; r < 4; ++r) {
        int row = rbase + r;
        float v = w_s[row] * (acc[i][j][r] + bias);
        if (EPI == 1) {
          scratch[(size_t)(sbase + m0 + row) * HD + col] = (_Float16)v;
        } else {
          if (m0 + row < ce)
            atomicAdd(&out[(size_t)tok_s[row] * HD + col], v);
        }
      }
    }
  }
}

// ---- Combine: out[t] = scratch[slot0] + scratch[slot1] ----
__global__ void moe_combine(const _Float16* __restrict__ scratch,
                            const int* __restrict__ slot_of,
                            float* __restrict__ out) {
  const int tid = threadIdx.x;
  const int t = blockIdx.x * 2 + (tid >> 7);
  const int c = (tid & 127) * 8;
  int sa = slot_of[2 * t], sb = slot_of[2 * t + 1];
  half8 a = *(const half8*)&scratch[(size_t)sa * HD + c];
  half8 b = *(const half8*)&scratch[(size_t)sb * HD + c];
  float* o = out + (size_t)t * HD + c;
  float4 o0 = {(float)a[0] + (float)b[0], (float)a[1] + (float)b[1],
               (float)a[2] + (float)b[2], (float)a[3] + (float)b[3]};
  float4 o1 = {(float)a[4] + (float)b[4], (float)a[5] + (float)b[5],
               (float)a[6] + (float)b[6], (float)a[7] + (float)b[7]};
  *(float4*)o = o0;
  *(float4*)(o + 4) = o1;
}

// ---- fallback GEMM (fp32 inline cvt, BK=32, atomic) for tiny ws ----
__global__ __launch_bounds__(256) void moe_gemm_f32(
    const float* __restrict__ Af, const float* __restrict__ Bf,
    const float* __restrict__ eb,
    const int* __restrict__ cntp, const int* __restrict__ base,
    const int* __restrict__ tok_list, const float* __restrict__ tok_w,
    float* __restrict__ out) {
  const int e = blockIdx.z;
  const int ce = cntp[e * 64];
  const int m0 = blockIdx.y * 128;
  if (m0 >= ce) return;
  const int sbase = base[e];
  const int n0 = blockIdx.x * 128;
  const int tid = threadIdx.x;
  const int lane = tid & 63;
  const int wid = tid >> 6;
  const int wm = wid & 1, wn = wid >> 1;
  __shared__ _Float16 A_s[128 * 32];
  __shared__ _Float16 B_s[128 * 32];
  __shared__ int tok_s[128];
  __shared__ float w_s[128];
  if (tid < 128) {
    int tk = 0; float w = 0.f;
    if (m0 + tid < ce) { tk = tok_list[sbase + m0 + tid]; w = tok_w[sbase + m0 + tid]; }
    tok_s[tid] = tk; w_s[tid] = w;
  }
  __syncthreads();
  floatx4 acc[4][4];
  floatx4 zero = {0.f, 0.f, 0.f, 0.f};
#pragma unroll
  for (int i = 0; i < 4; ++i)
#pragma unroll
    for (int j = 0; j < 4; ++j) acc[i][j] = zero;
  const size_t wbase = (size_t)e * HD * HD;
  for (int k0 = 0; k0 < HD; k0 += 32) {
#pragma unroll
    for (int q = 0; q < 4; ++q) {
      int s = tid + 256 * q;
      int row = s >> 3, kc = (s & 7) * 4;
      float4 va = *(const float4*)(Af + (size_t)tok_s[row] * HD + k0 + kc);
      half4v ha = {(_Float16)va.x, (_Float16)va.y, (_Float16)va.z, (_Float16)va.w};
      *(half4v*)&A_s[row * 32 + kc] = ha;
      float4 vb = *(const float4*)(Bf + wbase + (size_t)(n0 + row) * HD + k0 + kc);
      half4v hb = {(_Float16)vb.x, (_Float16)vb.y, (_Float16)vb.z, (_Float16)vb.w};
      *(half4v*)&B_s[row * 32 + kc] = hb;
    }
    __syncthreads();
    half8 afr[4], bfr[4];
#pragma unroll
    for (int i = 0; i < 4; ++i)
      afr[i] = *(const half8*)&A_s[(wm * 64 + i * 16 + (lane & 15)) * 32 + (lane >> 4) * 8];
#pragma unroll
    for (int j = 0; j < 4; ++j)
      bfr[j] = *(const half8*)&B_s[(wn * 64 + j * 16 + (lane & 15)) * 32 + (lane >> 4) * 8];
#pragma unroll
    for (int i = 0; i < 4; ++i)
#pragma unroll
      for (int j = 0; j < 4; ++j)
        acc[i][j] = __builtin_amdgcn_mfma_f32_16x16x32_f16(afr[i], bfr[j], acc[i][j], 0, 0, 0);
    __syncthreads();
  }
#pragma unroll
  for (int j = 0; j < 4; ++j) {
    int col = n0 + wn * 64 + j * 16 + (lane & 15);
    float bias = eb[e * HD + col];
#pragma unroll
    for (int i = 0; i < 4; ++i) {
      int rbase = wm * 64 + i * 16 + ((lane >> 4) << 2);
#pragma unroll
      for (int r = 0; r < 4; ++r) {
        int row = rbase + r;
        if (m0 + row < ce)
          atomicAdd(&out[(size_t)tok_s[row] * HD + col], w_s[row] * (acc[i][j][r] + bias));
      }
    }
  }
}

extern "C" void kernel_launch(void* const* d_in, const int* in_sizes, int n_in,
                              void* d_out, int out_size, void* d_ws, size_t ws_size,
                              hipStream_t stream) {
  (void)in_sizes; (void)n_in;
  const float* x  = (const float*)d_in[0];
  const float* rw = (const float*)d_in[1];
  const float* rb = (const float*)d_in[2];
  const float* ew = (const float*)d_in[3];
  const float* eb = (const float*)d_in[4];
  float* out = (float*)d_out;

  // ws layout
  char* w = (char*)d_ws;
  int*   cntp     = (int*)(w + 0);        // NE*64 ints (2 KB)
  int*   cnt2     = (int*)(w + 2048);     // NE*64 ints (2 KB)
  int*   basep    = (int*)(w + 4096);     // 8 ints (256 B)
  int*   tok_list = (int*)(w + 4352);             // SLOTS*4
  float* tok_w    = (float*)(w + 4352 + SLOTS*4); // SLOTS*4
  size_t off = 4352 + 2ull * SLOTS * 4;
  int*   epair    = (int*)(w + off);  off += TOK * 4;
  int*   slot_of  = (int*)(w + off);  off += TOK * 8;
  float* w1buf    = (float*)(w + off); off += TOK * 4;
  off = (off + 255) & ~255ull;
  size_t xh_off = off;
  size_t wh_off = xh_off + (size_t)TOK * HD * 2;
  size_t scr_off = wh_off + (size_t)NE * HD * HD * 2;
  size_t need16  = scr_off;
  size_t needscr = scr_off + (size_t)SLOTS * HD * 2;
  bool fast16 = ws_size >= need16;
  bool fastscr = ws_size >= needscr;

  hipMemsetAsync(cntp, 0, NE * 64 * sizeof(int), stream);
  if (!fastscr)
    hipMemsetAsync(d_out, 0, (size_t)out_size * sizeof(float), stream);

  _Float16* xh = fast16 ? (_Float16*)(w + xh_off) : nullptr;
  _Float16* wh = fast16 ? (_Float16*)(w + wh_off) : nullptr;
  _Float16* scr = fastscr ? (_Float16*)(w + scr_off) : nullptr;

  moe_score<<<TOK / 4, 256, 0, stream>>>(x, rw, rb, epair, w1buf, xh);
  moe_count<<<TOK / 256, 256, 0, stream>>>(epair, cntp);
  moe_prefix<<<1, 64, 0, stream>>>(cntp, cnt2, basep);
  moe_scatter<<<TOK / 256, 256, 0, stream>>>(epair, w1buf, cnt2, tok_list, tok_w, slot_of);

  dim3 grid(HD / 128, TOK / 128, NE);
  if (fast16) {
    int n4w = NE * HD * HD / 4;
    cvt_f32_f16<<<(n4w + 255) / 256, 256, 0, stream>>>(ew, wh, n4w);
    if (fastscr) {
      moe_gemm<1><<<grid, 256, 0, stream>>>(xh, wh, eb, cntp, basep,
                                            tok_list, tok_w, scr, out);
      moe_combine<<<TOK / 2, 256, 0, stream>>>(scr, slot_of, out);
    } else {
      moe_gemm<0><<<grid, 256, 0, stream>>>(xh, wh, eb, cntp, basep,
                                            tok_list, tok_w, nullptr, out);
    }
  } else {
    moe_gemm_f32<<<grid, 256, 0, stream>>>(x, ew, eb, cntp, basep,
                                           tok_list, tok_w, out);
  }
}